// Round 5
// baseline (171.825 us; speedup 1.0000x reference)
//
#include <hip/hip_runtime.h>

#define IMG     512
#define VALID   506          // IMG - 6
#define NPLANES 96           // 32 * 3
#define R       8            // output rows per wave-band
#define NBANDS  64           // 64 * 8 = 512 >= 506

struct Q { float4 x0, x1, y0, y1; };

__device__ __forceinline__ float shfl_next(float v, int baddr) {
    return __int_as_float(__builtin_amdgcn_ds_bpermute(baddr, __float_as_int(v)));
}

__device__ __forceinline__ void addv(float4& V, const float4 p) {
    V.x += p.x; V.y += p.y; V.z += p.z; V.w += p.w;
}
__device__ __forceinline__ void subv(float4& V, const float4 p) {
    V.x -= p.x; V.y -= p.y; V.z -= p.z; V.w -= p.w;
}
__device__ __forceinline__ void addmul(float4& V, const float4 p, const float4 q) {
    V.x = fmaf(p.x, q.x, V.x); V.y = fmaf(p.y, q.y, V.y);
    V.z = fmaf(p.z, q.z, V.z); V.w = fmaf(p.w, q.w, V.w);
}
__device__ __forceinline__ void submul(float4& V, const float4 p, const float4 q) {
    V.x = fmaf(-p.x, q.x, V.x); V.y = fmaf(-p.y, q.y, V.y);
    V.z = fmaf(-p.z, q.z, V.z); V.w = fmaf(-p.w, q.w, V.w);
}

// horizontal 7-tap sliding sums over this lane's 8 cols + 6 halo cols from lane+1
__device__ __forceinline__ void hsum7(const float4 A, const float4 B, int baddr, float o[8]) {
    float n0 = shfl_next(A.x, baddr);
    float n1 = shfl_next(A.y, baddr);
    float n2 = shfl_next(A.z, baddr);
    float n3 = shfl_next(A.w, baddr);
    float n4 = shfl_next(B.x, baddr);
    float n5 = shfl_next(B.y, baddr);
    o[0] = ((A.x + A.y) + (A.z + A.w)) + ((B.x + B.y) + B.z);
    o[1] = (o[0] - A.x) + B.w;
    o[2] = (o[1] - A.y) + n0;
    o[3] = (o[2] - A.z) + n1;
    o[4] = (o[3] - A.w) + n2;
    o[5] = (o[4] - B.x) + n3;
    o[6] = (o[5] - B.y) + n4;
    o[7] = (o[6] - B.z) + n5;
}

__global__ __launch_bounds__(256, 4) void ssim_wave_kernel(
    const float* __restrict__ pred,
    const float* __restrict__ target,
    double* __restrict__ accum)
{
    __shared__ float wsum[4];

    const int t     = threadIdx.x;
    const int lane  = t & 63;
    const int wv    = t >> 6;
    const int band  = blockIdx.x * 4 + wv;
    const int plane = blockIdx.y;
    const int row0  = band * R;
    const int col   = lane << 3;               // this lane's 8 columns

    const size_t pbase = (size_t)plane * (IMG * IMG);
    const float* __restrict__ pp = pred   + pbase + col;
    const float* __restrict__ pt = target + pbase + col;

    const int baddr = ((lane + 1) & 63) << 2;  // ds_bpermute addr: lane+1

    float4 z = make_float4(0.f, 0.f, 0.f, 0.f);
    float4 Vx_a = z, Vx_b = z, Vy_a = z, Vy_b = z;
    float4 Vss_a = z, Vss_b = z, Vxy_a = z, Vxy_b = z;   // Vss = Vxx + Vyy merged

#define LOADQ(q, r) do { int _rr = (r) < (IMG - 1) ? (r) : (IMG - 1);              \
    const float4* _p  = reinterpret_cast<const float4*>(pp + (size_t)_rr * IMG);  \
    const float4* _q2 = reinterpret_cast<const float4*>(pt + (size_t)_rr * IMG);  \
    q.x0 = _p[0]; q.x1 = _p[1]; q.y0 = _q2[0]; q.y1 = _q2[1]; } while (0)

#define ACCQ(q) do {                                                   \
    addv(Vx_a, q.x0); addv(Vx_b, q.x1); addv(Vy_a, q.y0); addv(Vy_b, q.y1); \
    addmul(Vss_a, q.x0, q.x0); addmul(Vss_b, q.x1, q.x1);              \
    addmul(Vss_a, q.y0, q.y0); addmul(Vss_b, q.y1, q.y1);              \
    addmul(Vxy_a, q.x0, q.y0); addmul(Vxy_b, q.x1, q.y1); } while (0)

#define SUBQ(q) do {                                                   \
    subv(Vx_a, q.x0); subv(Vx_b, q.x1); subv(Vy_a, q.y0); subv(Vy_b, q.y1); \
    submul(Vss_a, q.x0, q.x0); submul(Vss_b, q.x1, q.x1);              \
    submul(Vss_a, q.y0, q.y0); submul(Vss_b, q.y1, q.y1);              \
    submul(Vxy_a, q.x0, q.y0); submul(Vxy_b, q.x1, q.y1); } while (0)

    const float c1 = 0.9604f;   // (0.01*2)^2 * 49^2
    const float c2 = 8.4672f;   // (0.03*2)^2 * 48*49
    float local = 0.f;

#define HSSIM(i) do { if ((row0 + (i)) < VALID) {                      \
    float hx[8], hy[8], hss[8], hxy[8];                                \
    hsum7(Vx_a,  Vx_b,  baddr, hx);                                    \
    hsum7(Vy_a,  Vy_b,  baddr, hy);                                    \
    hsum7(Vss_a, Vss_b, baddr, hss);                                   \
    hsum7(Vxy_a, Vxy_b, baddr, hxy);                                   \
    _Pragma("unroll")                                                  \
    for (int j = 0; j < 8; ++j) {                                      \
        float t1 = hx[j] * hy[j];                                      \
        float t2 = fmaf(hx[j], hx[j], hy[j] * hy[j]);                  \
        float n1 = fmaf(2.f, t1, c1);                                  \
        float d1 = t2 + c1;                                            \
        float n2 = fmaf(-2.f, t1, fmaf(98.f, hxy[j], c2));             \
        float d2 = fmaf(49.f, hss[j], c2) - t2;                        \
        float S  = __fdividef(n1 * n2, d1 * d2);                       \
        local += (col + j < VALID) ? S : 0.f;                          \
    } } } while (0)

    // ---- prologue: 5 row-loads issued upfront (deep MLP); rows 0,1 kept
    //      in slots A,B and reused as the first two subtract rows ----
    Q A, B, N, H1, H2;
    LOADQ(A,  row0);          // row 0  (also sr(1))
    LOADQ(B,  row0 + 1);      // row 1  (also sr(2))
    LOADQ(N,  row0 + 2);      // row 2
    LOADQ(H1, row0 + 3);      // row 3
    LOADQ(H2, row0 + 4);      // row 4
    ACCQ(A); ACCQ(B); ACCQ(N);
    LOADQ(N,  row0 + 5);      // row 5
    ACCQ(H1); ACCQ(H2);
    LOADQ(H1, row0 + 6);      // row 6 (in flight across row-5 accumulate)
    ACCQ(N);                  // row 5
    LOADQ(N,  row0 + 7);      // step-1's new row, issued early

    // ---- 8 pipelined steps; slot issue->consume distance = 2 steps ----
    // S0
    ACCQ(H1);                                             HSSIM(0);
    // S1
    ACCQ(N); LOADQ(N, row0 + 8);  SUBQ(A); LOADQ(A, row0 + 2); HSSIM(1);
    // S2
    ACCQ(N); LOADQ(N, row0 + 9);  SUBQ(B); LOADQ(B, row0 + 3); HSSIM(2);
    // S3
    ACCQ(N); LOADQ(N, row0 + 10); SUBQ(A); LOADQ(A, row0 + 4); HSSIM(3);
    // S4
    ACCQ(N); LOADQ(N, row0 + 11); SUBQ(B); LOADQ(B, row0 + 5); HSSIM(4);
    // S5
    ACCQ(N); LOADQ(N, row0 + 12); SUBQ(A); LOADQ(A, row0 + 6); HSSIM(5);
    // S6
    ACCQ(N); LOADQ(N, row0 + 13); SUBQ(B);                     HSSIM(6);
    // S7
    ACCQ(N);                      SUBQ(A);                     HSSIM(7);

    // wave reduce -> cross-wave -> one atomic per block, scattered per plane
    #pragma unroll
    for (int off = 32; off > 0; off >>= 1)
        local += __shfl_down(local, off, 64);
    if (lane == 0) wsum[wv] = local;
    __syncthreads();
    if (t == 0)
        atomicAdd(&accum[plane], (double)(wsum[0] + wsum[1] + wsum[2] + wsum[3]));
}

__global__ void ssim_finalize_kernel(const double* __restrict__ accum,
                                     float* __restrict__ out)
{
    const int l = threadIdx.x;           // 64 threads = 1 wave
    double s = accum[l];
    if (l < NPLANES - 64) s += accum[64 + l];
    #pragma unroll
    for (int off = 32; off > 0; off >>= 1)
        s += __shfl_down(s, off, 64);
    if (l == 0) {
        const double n_valid = (double)NPLANES * (double)VALID * (double)VALID;
        out[0] = (float)(1.0 - s / n_valid);
    }
}

extern "C" void kernel_launch(void* const* d_in, const int* in_sizes, int n_in,
                              void* d_out, int out_size, void* d_ws, size_t ws_size,
                              hipStream_t stream) {
    const float* pred   = (const float*)d_in[0];
    const float* target = (const float*)d_in[1];
    float* out = (float*)d_out;
    double* accum = (double*)d_ws;

    hipMemsetAsync(d_ws, 0, NPLANES * sizeof(double), stream);

    dim3 grid(NBANDS / 4, NPLANES);   // 16 x 96 = 1536 blocks, 4 wave-bands each
    ssim_wave_kernel<<<grid, 256, 0, stream>>>(pred, target, accum);
    ssim_finalize_kernel<<<1, 64, 0, stream>>>(accum, out);
}

// Round 6
// 82.312 us; speedup vs baseline: 2.0875x; 2.0875x over previous
//
#include <hip/hip_runtime.h>

#define IMG     512
#define VALID   506          // IMG - 6
#define NPLANES 96           // 32 * 3
#define R       10           // output rows per wave-band
#define NBANDS  51           // ceil(506/10)

__device__ __forceinline__ float shfl_next(float v, int baddr) {
    return __int_as_float(__builtin_amdgcn_ds_bpermute(baddr, __float_as_int(v)));
}

__device__ __forceinline__ void addv(float4& V, const float4 p) {
    V.x += p.x; V.y += p.y; V.z += p.z; V.w += p.w;
}
__device__ __forceinline__ void subv(float4& V, const float4 p) {
    V.x -= p.x; V.y -= p.y; V.z -= p.z; V.w -= p.w;
}
__device__ __forceinline__ void addmul(float4& V, const float4 p, const float4 q) {
    V.x = fmaf(p.x, q.x, V.x); V.y = fmaf(p.y, q.y, V.y);
    V.z = fmaf(p.z, q.z, V.z); V.w = fmaf(p.w, q.w, V.w);
}
__device__ __forceinline__ void submul(float4& V, const float4 p, const float4 q) {
    V.x = fmaf(-p.x, q.x, V.x); V.y = fmaf(-p.y, q.y, V.y);
    V.z = fmaf(-p.z, q.z, V.z); V.w = fmaf(-p.w, q.w, V.w);
}

// horizontal 7-tap sliding sums over this lane's 8 cols + 6 halo cols from lane+1
__device__ __forceinline__ void hsum7(const float4 A, const float4 B, int baddr, float o[8]) {
    float n0 = shfl_next(A.x, baddr);
    float n1 = shfl_next(A.y, baddr);
    float n2 = shfl_next(A.z, baddr);
    float n3 = shfl_next(A.w, baddr);
    float n4 = shfl_next(B.x, baddr);
    float n5 = shfl_next(B.y, baddr);
    o[0] = ((A.x + A.y) + (A.z + A.w)) + ((B.x + B.y) + B.z);
    o[1] = (o[0] - A.x) + B.w;
    o[2] = (o[1] - A.y) + n0;
    o[3] = (o[2] - A.z) + n1;
    o[4] = (o[3] - A.w) + n2;
    o[5] = (o[4] - B.x) + n3;
    o[6] = (o[5] - B.y) + n4;
    o[7] = (o[6] - B.z) + n5;
}

#define LOADROW(x0, x1, y0, y1, r) do {                                         \
    const float4* _p = reinterpret_cast<const float4*>(pp + (size_t)(r) * IMG); \
    const float4* _q = reinterpret_cast<const float4*>(pt + (size_t)(r) * IMG); \
    x0 = _p[0]; x1 = _p[1]; y0 = _q[0]; y1 = _q[1]; } while (0)

__global__ __launch_bounds__(128) void ssim_wave_kernel(
    const float* __restrict__ pred,
    const float* __restrict__ target,
    double* __restrict__ accum)
{
    const int t     = threadIdx.x;
    const int lane  = t & 63;
    const int wv    = t >> 6;
    const int band  = blockIdx.x * 2 + wv;      // 0..51 (51 = pad band)
    const int plane = blockIdx.y;
    const int row0  = band * R;
    const int col   = lane << 3;                // this lane's 8 columns

    if (row0 >= VALID) return;                  // pad band: no barriers used, safe

    const size_t pbase = (size_t)plane * (IMG * IMG);
    const float* __restrict__ pp = pred   + pbase + col;
    const float* __restrict__ pt = target + pbase + col;

    const int baddr = ((lane + 1) & 63) << 2;   // ds_bpermute addr: lane+1

    float4 z = make_float4(0.f, 0.f, 0.f, 0.f);
    float4 Vx_a = z, Vx_b = z, Vy_a = z, Vy_b = z;
    float4 Vss_a = z, Vss_b = z, Vxy_a = z, Vxy_b = z;   // Vss = Vxx + Vyy merged

    float4 nx0, nx1, ny0, ny1;                  // prefetched incoming row
    LOADROW(nx0, nx1, ny0, ny1, row0);

    // ---- prologue: accumulate input rows row0 .. row0+5 ----
    #pragma unroll
    for (int k = 0; k < 6; ++k) {
        float4 px0 = nx0, px1 = nx1, py0 = ny0, py1 = ny1;
        LOADROW(nx0, nx1, ny0, ny1, row0 + k + 1);    // k=5 -> row0+6 (iter-0 row)
        addv(Vx_a, px0);  addv(Vx_b, px1);
        addv(Vy_a, py0);  addv(Vy_b, py1);
        addmul(Vss_a, px0, px0); addmul(Vss_b, px1, px1);
        addmul(Vss_a, py0, py0); addmul(Vss_b, py1, py1);
        addmul(Vxy_a, px0, py0); addmul(Vxy_b, px1, py1);
    }

    // old-row prefetch for iter 1 (iter 0 has no subtract)
    float4 pox0, pox1, poy0, poy1;
    LOADROW(pox0, pox1, poy0, poy1, row0);

    const float c1 = 0.9604f;   // (0.01*2)^2 * 49^2
    const float c2 = 8.4672f;   // (0.03*2)^2 * 48*49
    float local = 0.f;

    #pragma unroll
    for (int i = 0; i < R; ++i) {
        float4 px0 = nx0, px1 = nx1, py0 = ny0, py1 = ny1;
        float4 ox0 = pox0, ox1 = pox1, oy0 = poy0, oy1 = poy1;

        // prefetch for iter i+1: incoming row row0+7+i (clamped), old row row0+i
        if (i < R - 1) {
            int rn = row0 + 7 + i; rn = rn < IMG - 1 ? rn : IMG - 1;
            LOADROW(nx0, nx1, ny0, ny1, rn);
            if (i > 0) LOADROW(pox0, pox1, poy0, poy1, row0 + i);
        }

        // vertical sliding update
        addv(Vx_a, px0);  addv(Vx_b, px1);
        addv(Vy_a, py0);  addv(Vy_b, py1);
        addmul(Vss_a, px0, px0); addmul(Vss_b, px1, px1);
        addmul(Vss_a, py0, py0); addmul(Vss_b, py1, py1);
        addmul(Vxy_a, px0, py0); addmul(Vxy_b, px1, py1);
        if (i > 0) {
            subv(Vx_a, ox0);  subv(Vx_b, ox1);
            subv(Vy_a, oy0);  subv(Vy_b, oy1);
            submul(Vss_a, ox0, ox0); submul(Vss_b, ox1, ox1);
            submul(Vss_a, oy0, oy0); submul(Vss_b, oy1, oy1);
            submul(Vxy_a, ox0, oy0); submul(Vxy_b, ox1, oy1);
        }

        const bool row_ok = (row0 + i) < VALID;   // wave-uniform
        if (row_ok) {
            float hx[8], hy[8], hss[8], hxy[8];
            hsum7(Vx_a,  Vx_b,  baddr, hx);
            hsum7(Vy_a,  Vy_b,  baddr, hy);
            hsum7(Vss_a, Vss_b, baddr, hss);
            hsum7(Vxy_a, Vxy_b, baddr, hxy);
            #pragma unroll
            for (int j = 0; j < 8; ++j) {
                float t1 = hx[j] * hy[j];
                float t2 = fmaf(hx[j], hx[j], hy[j] * hy[j]);
                float n1 = fmaf(2.f, t1, c1);
                float d1 = t2 + c1;
                float n2 = fmaf(-2.f, t1, fmaf(98.f, hxy[j], c2));
                float d2 = fmaf(49.f, hss[j], c2) - t2;
                float S  = __fdividef(n1 * n2, d1 * d2);
                local += (col + j < VALID) ? S : 0.f;
            }
        }
    }

    // per-wave reduce -> one atomic per wave, scattered per plane (no barriers)
    #pragma unroll
    for (int off = 32; off > 0; off >>= 1)
        local += __shfl_down(local, off, 64);
    if (lane == 0)
        atomicAdd(&accum[plane], (double)local);
}

__global__ void ssim_finalize_kernel(const double* __restrict__ accum,
                                     float* __restrict__ out)
{
    const int l = threadIdx.x;           // 64 threads = 1 wave
    double s = accum[l];
    if (l < NPLANES - 64) s += accum[64 + l];
    #pragma unroll
    for (int off = 32; off > 0; off >>= 1)
        s += __shfl_down(s, off, 64);
    if (l == 0) {
        const double n_valid = (double)NPLANES * (double)VALID * (double)VALID;
        out[0] = (float)(1.0 - s / n_valid);
    }
}

extern "C" void kernel_launch(void* const* d_in, const int* in_sizes, int n_in,
                              void* d_out, int out_size, void* d_ws, size_t ws_size,
                              hipStream_t stream) {
    const float* pred   = (const float*)d_in[0];
    const float* target = (const float*)d_in[1];
    float* out = (float*)d_out;
    double* accum = (double*)d_ws;

    hipMemsetAsync(d_ws, 0, NPLANES * sizeof(double), stream);

    // 26 x 96 blocks, 2 independent wave-bands per 128-thread block:
    // 4896 active waves ~= one full residency generation (20 waves/CU)
    dim3 grid((NBANDS + 1) / 2, NPLANES);
    ssim_wave_kernel<<<grid, 128, 0, stream>>>(pred, target, accum);
    ssim_finalize_kernel<<<1, 64, 0, stream>>>(accum, out);
}